// Round 7
// baseline (86.052 us; speedup 1.0000x reference)
//
#include <hip/hip_runtime.h>

// SpanMaskGenerator: B=256, S=131072, 4 spans/batch.
// Outputs (concatenated int32): context_mask [B,S], target_mask [B,S],
// padded_positions [B,S] (masked positions ascending, sentinel = S).
//
// Union of 4 start-sorted spans = <=4 disjoint ascending segments
// [max(ss[i],M_{i-1}), max(ee[i],M_{i-1})) with M = running max of ends.
// padded_positions is a closed-form per-index lookup -> pure streaming map.
//
// R7: PERSISTENT fill-shaped blocks. History:
//   R1: plain, 16k short blocks           -> 68.8 us (5.85 TB/s)
//   R3: nt, 64B lane stride               -> 526 us (write amp 2.8x)
//   R4: nt, wave-contiguous               -> 81.5 us (nt drain slow)
//   R5: plain, wave-contiguous, 8k blocks -> 78.7 us
//   R6: one stream per block, 12k blocks  -> 79.5 us (stream-alias refuted)
// Fill kernel: 6.97 TB/s at 11% occupancy, tiny persistent loop. Gap theory:
// short-lived blocks pay setup before ~12 stores; amortization + ramp ~= the
// 10-20 us gap. Fix: 2048 co-resident blocks, one contiguous 192KB slice
// each, flat-index bit-decode (all pow2), setup recomputed only when b
// changes (<=1 per block).

constexpr int S_LEN   = 131072;          // 2^17
constexpr int BATCH   = 256;
constexpr int TOTAL   = 3 * BATCH * S_LEN;   // 100,663,296 ints (3*2^25)
constexpr int TPB     = 256;
constexpr int NBLOCKS = 2048;
constexpr int PER_BLK = TOTAL / NBLOCKS;     // 49152 ints = 192KB
constexpr int PER_IT  = TPB * 4;             // 4096 ints per iteration
constexpr int NITER   = PER_BLK / PER_IT;    // 12

typedef int int4v __attribute__((ext_vector_type(4)));

__global__ __launch_bounds__(TPB) void span_mask_kernel(
    const float* __restrict__ scales_u,
    const float* __restrict__ starts_u,
    int* __restrict__ out)
{
    const int base = blockIdx.x * PER_BLK + threadIdx.x * 4;

    int prev_b = -1;
    // span state (persisted across iterations; all statically indexed)
    int s0_ = 0, s1_ = 0, s2_ = 0, s3_ = 0;     // sorted starts
    int e0_ = 0, e1_ = 0, e2_ = 0, e3_ = 0;     // matching ends
    int L0 = 0, L1 = 0, L2 = 0, L3 = 0;         // segment left edges
    int c1 = 0, c2 = 0, c3 = 0, total = 0;      // cumulative counts

    for (int it = 0; it < NITER; ++it) {
        const int flat  = base + it * PER_IT;
        const int which = flat >> 25;            // 0..2 (uniform per chunk)
        const int b     = (flat >> 17) & 255;    // batch row
        const int s     = flat & (S_LEN - 1);    // position

        if (b != prev_b) {                       // wave-uniform, <=2 per block
            prev_b = b;
            int ss[4], ee[4];
#pragma unroll
            for (int t = 0; t < 4; ++t) {
                float u  = scales_u[b * 4 + t];
                float r  = starts_u[b * 4 + t];
                // exact f32 replication: separate mul/add, trunc casts
                float sc = __fadd_rn(0.15f, __fmul_rn(u, 0.05f));
                int len  = (int)__fmul_rn(sc, 131072.0f);
                if (len < 1) len = 1;
                int mx   = S_LEN - len; if (mx < 0) mx = 0;
                int st   = (int)__fmul_rn(r, __fadd_rn((float)mx, 1.0f));
                int en   = st + len; if (en > S_LEN) en = S_LEN;
                ss[t] = st; ee[t] = en;
            }
#define CSWAP(i, j)                                                        \
            if (ss[i] > ss[j]) {                                           \
                int t0 = ss[i]; ss[i] = ss[j]; ss[j] = t0;                 \
                int t1 = ee[i]; ee[i] = ee[j]; ee[j] = t1;                 \
            }
            CSWAP(0, 1) CSWAP(2, 3) CSWAP(0, 2) CSWAP(1, 3) CSWAP(1, 2)
#undef CSWAP
            s0_ = ss[0]; s1_ = ss[1]; s2_ = ss[2]; s3_ = ss[3];
            e0_ = ee[0]; e1_ = ee[1]; e2_ = ee[2]; e3_ = ee[3];
            const int R0 = e0_;
            L0 = s0_;
            L1 = max(s1_, R0); const int R1 = max(e1_, R0);
            L2 = max(s2_, R1); const int R2 = max(e2_, R1);
            L3 = max(s3_, R2); const int R3 = max(e3_, R2);
            c1 = R0 - L0;
            c2 = c1 + (R1 - L1);
            c3 = c2 + (R2 - L2);
            total = c3 + (R3 - L3);
        }

        int v0, v1, v2, v3;
        if (which == 2) {
            // padded_positions[k]: k-th masked position, else sentinel S_LEN
#define POSV(K, OUTV)                                                      \
            {                                                              \
                const int k = (K); int p;                                  \
                if      (k >= total) p = S_LEN;                            \
                else if (k >= c3)    p = L3 + (k - c3);                    \
                else if (k >= c2)    p = L2 + (k - c2);                    \
                else if (k >= c1)    p = L1 + (k - c1);                    \
                else                 p = L0 + k;                           \
                OUTV = p;                                                  \
            }
            POSV(s,     v0) POSV(s + 1, v1) POSV(s + 2, v2) POSV(s + 3, v3)
#undef POSV
        } else {
            const int flip = which ^ 1;          // ctx: cov^1, tgt: cov
#define COVV(K, OUTV)                                                      \
            {                                                              \
                const int k = (K);                                         \
                const int cov =                                            \
                    ((k >= s0_) & (k < e0_)) | ((k >= s1_) & (k < e1_)) |  \
                    ((k >= s2_) & (k < e2_)) | ((k >= s3_) & (k < e3_));   \
                OUTV = cov ^ flip;                                         \
            }
            COVV(s,     v0) COVV(s + 1, v1) COVV(s + 2, v2) COVV(s + 3, v3)
#undef COVV
        }

        int4v v4 = { v0, v1, v2, v3 };
        *(reinterpret_cast<int4v*>(out + flat)) = v4;
    }
}

extern "C" void kernel_launch(void* const* d_in, const int* in_sizes, int n_in,
                              void* d_out, int out_size, void* d_ws, size_t ws_size,
                              hipStream_t stream)
{
    const float* scales_u = (const float*)d_in[0];
    const float* starts_u = (const float*)d_in[1];
    // d_in[2]/d_in[3] are batch_size=256 / seq_len=131072 scalars (fixed).
    span_mask_kernel<<<dim3(NBLOCKS), dim3(TPB), 0, stream>>>(
        scales_u, starts_u, (int*)d_out);
}

// Round 8
// 82.555 us; speedup vs baseline: 1.0424x; 1.0424x over previous
//
#include <hip/hip_runtime.h>

// SpanMaskGenerator: B=256, S=131072, 4 spans/batch.
// Outputs (concatenated int32): context_mask [B,S], target_mask [B,S],
// padded_positions [B,S] (masked positions ascending, sentinel = S).
//
// Union of 4 start-sorted spans = <=4 disjoint ascending segments
// [max(ss[i],M_{i-1}), max(ee[i],M_{i-1})) with M = running max of ends.
// padded_positions is a closed-form per-index lookup -> pure streaming map.
//
// R8: GRID-STRIDE SWEEP (fill-kernel pattern). History:
//   R1: 16k short blocks, x-minor sweep     -> 68.8 us (5.85 TB/s)
//   R3: nt + 64B lane stride                -> 526 us (2.8x write amp)
//   R4: nt wave-contig                      -> 81.5 us (nt drain slow)
//   R5: plain wave-contig, 8k blocks        -> 78.7 us
//   R6: one stream per block                -> 79.5 us
//   R7: persistent private slices           -> 86.1 us (2048 independent
//       streams -> DRAM page thrash; worst)
// Model: write BW ~ coherence of the global store front. Fill kernel
// (grid-stride, ONE moving front) = 6.9 TB/s. This kernel reproduces it:
// iteration it, block g -> contiguous chunk (it*2048+g)*8192 ints; the grid
// forms a single 64MB window sweeping the output 6 times.

constexpr int S_LEN   = 131072;              // 2^17
constexpr int BATCH   = 256;
constexpr int TOTAL   = 3 * BATCH * S_LEN;   // 3*2^25 ints
constexpr int TPB     = 256;
constexpr int NBLOCKS = 2048;
constexpr int CHUNK   = 8192;                // ints per block-iteration (32KB)
constexpr int WINDOW  = NBLOCKS * CHUNK;     // 2^24 ints
constexpr int NITER   = TOTAL / WINDOW;      // 6

typedef int int4v __attribute__((ext_vector_type(4)));

__global__ __launch_bounds__(TPB) void span_mask_kernel(
    const float* __restrict__ scales_u,
    const float* __restrict__ starts_u,
    int* __restrict__ out)
{
    for (int it = 0; it < NITER; ++it) {
        const int chunk0 = (it * NBLOCKS + blockIdx.x) * CHUNK;
        const int which  = chunk0 >> 25;           // 0..2, uniform per chunk
        const int b      = (chunk0 >> 17) & 255;   // uniform per chunk
        const int sbase  = chunk0 & (S_LEN - 1);   // chunk-aligned

        // ---- per-chunk span setup (uniform; scalar-side; 6x per block) ----
        // Exact f32 replication: separate mul/add (no contraction), trunc.
        int ss[4], ee[4];
#pragma unroll
        for (int t = 0; t < 4; ++t) {
            float u  = scales_u[b * 4 + t];
            float r  = starts_u[b * 4 + t];
            float sc = __fadd_rn(0.15f, __fmul_rn(u, 0.05f));
            int len  = (int)__fmul_rn(sc, 131072.0f);
            if (len < 1) len = 1;
            int mx   = S_LEN - len; if (mx < 0) mx = 0;
            int st   = (int)__fmul_rn(r, __fadd_rn((float)mx, 1.0f));
            int en   = st + len; if (en > S_LEN) en = S_LEN;
            ss[t] = st; ee[t] = en;
        }
#define CSWAP(i, j)                                                        \
        if (ss[i] > ss[j]) {                                               \
            int t0 = ss[i]; ss[i] = ss[j]; ss[j] = t0;                     \
            int t1 = ee[i]; ee[i] = ee[j]; ee[j] = t1;                     \
        }
        CSWAP(0, 1) CSWAP(2, 3) CSWAP(0, 2) CSWAP(1, 3) CSWAP(1, 2)
#undef CSWAP
        const int L0 = ss[0],          R0 = ee[0];
        const int L1 = max(ss[1], R0), R1 = max(ee[1], R0);
        const int L2 = max(ss[2], R1), R2 = max(ee[2], R1);
        const int L3 = max(ss[3], R2), R3 = max(ee[3], R2);
        const int c1 = R0 - L0;
        const int c2 = c1 + (R1 - L1);
        const int c3 = c2 + (R2 - L2);
        const int total = c3 + (R3 - L3);

        if (which < 2) {
            const int flip = which ^ 1;            // ctx: cov^1, tgt: cov
#pragma unroll
            for (int k = 0; k < CHUNK / (TPB * 4); ++k) {   // 8 stores
                const int off = k * (TPB * 4) + threadIdx.x * 4;
                const int s   = sbase + off;
                int v[4];
#pragma unroll
                for (int j = 0; j < 4; ++j) {
                    const int x = s + j;
                    const int cov =
                        ((x >= ss[0]) & (x < ee[0])) | ((x >= ss[1]) & (x < ee[1])) |
                        ((x >= ss[2]) & (x < ee[2])) | ((x >= ss[3]) & (x < ee[3]));
                    v[j] = cov ^ flip;
                }
                int4v v4 = { v[0], v[1], v[2], v[3] };
                *(reinterpret_cast<int4v*>(out + chunk0 + off)) = v4;
            }
        } else {
#pragma unroll
            for (int k = 0; k < CHUNK / (TPB * 4); ++k) {   // 8 stores
                const int off = k * (TPB * 4) + threadIdx.x * 4;
                const int s   = sbase + off;
                int v[4];
#pragma unroll
                for (int j = 0; j < 4; ++j) {
                    const int x = s + j;
                    int p;
                    if      (x >= total) p = S_LEN;
                    else if (x >= c3)    p = L3 + (x - c3);
                    else if (x >= c2)    p = L2 + (x - c2);
                    else if (x >= c1)    p = L1 + (x - c1);
                    else                 p = L0 + x;
                    v[j] = p;
                }
                int4v v4 = { v[0], v[1], v[2], v[3] };
                *(reinterpret_cast<int4v*>(out + chunk0 + off)) = v4;
            }
        }
    }
}

extern "C" void kernel_launch(void* const* d_in, const int* in_sizes, int n_in,
                              void* d_out, int out_size, void* d_ws, size_t ws_size,
                              hipStream_t stream)
{
    const float* scales_u = (const float*)d_in[0];
    const float* starts_u = (const float*)d_in[1];
    // d_in[2]/d_in[3] are batch_size=256 / seq_len=131072 scalars (fixed).
    span_mask_kernel<<<dim3(NBLOCKS), dim3(TPB), 0, stream>>>(
        scales_u, starts_u, (int*)d_out);
}

// Round 9
// 68.871 us; speedup vs baseline: 1.2495x; 1.1987x over previous
//
#include <hip/hip_runtime.h>

// SpanMaskGenerator: B=256, S=131072, 4 spans/batch.
// Outputs (concatenated int32): context_mask [B,S], target_mask [B,S],
// padded_positions [B,S] (masked positions ascending, sentinel = S).
//
// Union of 4 start-sorted spans = <=4 disjoint ascending segments
// [max(ss[i],M_{i-1}), max(ee[i],M_{i-1})) with M = running max of ends.
// padded_positions is a closed-form per-index lookup -> pure streaming map.
//
// R9: REVERT to R1 verbatim (reproducibility check of the best result).
// Ledger (plain stores unless noted):
//   R1: ITEMS=8, 16k blocks, lane-stride-32B   -> 68.8 us (5.85 TB/s)  BEST
//   R3: nt, 64B lane stride                    -> 526 us (2.8x write amp)
//   R4: nt, wave-contiguous                    -> 81.5 us
//   R5: wave-contiguous, 8k blocks             -> 78.7 us
//   R6: one stream per block                   -> 79.5 us
//   R7: persistent private 192KB slices        -> 86.1 us
//   R8: grid-stride single-front sweep         -> 82.6 us
// All four mechanistic theories for the R1 gap (write-combining, stream
// aliasing, setup amortization, front coherence) were refuted by R5-R8.
// Remaining hypothesis: R1's config is genuinely best (or best-equal within
// noise). Reproduce it exactly before drawing the roofline.

constexpr int S_LEN = 131072;
constexpr int NBLK  = 4;
constexpr int TPB   = 256;
constexpr int ITEMS = 8;

__global__ __launch_bounds__(TPB) void span_mask_kernel(
    const float* __restrict__ scales_u,
    const float* __restrict__ starts_u,
    int* __restrict__ out,
    int batch)
{
    const int b = blockIdx.y;

    // ---- per-batch span computation (uniform across all threads; cheap) ----
    // Exact f32 replication of the reference: separate mul/add (no fma
    // contraction), truncating int casts.
    int ss[NBLK], ee[NBLK];
#pragma unroll
    for (int t = 0; t < NBLK; ++t) {
        float u  = scales_u[b * NBLK + t];
        float r  = starts_u[b * NBLK + t];
        float sc = __fadd_rn(0.15f, __fmul_rn(u, 0.05f));      // U(0.15,0.2)
        int len  = (int)__fmul_rn(sc, 131072.0f);              // trunc
        if (len < 1) len = 1;
        int mx   = S_LEN - len; if (mx < 0) mx = 0;
        int st   = (int)__fmul_rn(r, __fadd_rn((float)mx, 1.0f)); // trunc
        int en   = st + len; if (en > S_LEN) en = S_LEN;
        ss[t] = st; ee[t] = en;
    }

    // ---- sort 4 spans by start (sorting network, static indices only) ----
#define CSWAP(i, j)                                                        \
    if (ss[i] > ss[j]) {                                                   \
        int t0 = ss[i]; ss[i] = ss[j]; ss[j] = t0;                         \
        int t1 = ee[i]; ee[i] = ee[j]; ee[j] = t1;                         \
    }
    CSWAP(0, 1) CSWAP(2, 3) CSWAP(0, 2) CSWAP(1, 3) CSWAP(1, 2)
#undef CSWAP

    // ---- marginal-contribution segments (disjoint, ascending) ----
    const int L0 = ss[0],          R0 = ee[0];
    const int L1 = max(ss[1], R0), R1 = max(ee[1], R0);
    const int L2 = max(ss[2], R1), R2 = max(ee[2], R1);
    const int L3 = max(ss[3], R2), R3 = max(ee[3], R2);
    const int c1 = R0 - L0;                 // cumulative masked counts
    const int c2 = c1 + (R1 - L1);
    const int c3 = c2 + (R2 - L2);
    const int total = c3 + (R3 - L3);

    const size_t BS   = (size_t)batch * S_LEN;
    const size_t base = (size_t)b * S_LEN;
    int* __restrict__ ctx = out + base;            // context_mask
    int* __restrict__ tgt = out + BS + base;       // target_mask
    int* __restrict__ pad = out + 2 * BS + base;   // padded_positions

    const int p0 = (blockIdx.x * TPB + threadIdx.x) * ITEMS;

    int tv[ITEMS], cv[ITEMS], pv[ITEMS];
#pragma unroll
    for (int i = 0; i < ITEMS; ++i) {
        const int s = p0 + i;
        const int cov =
            ((s >= ss[0]) & (s < ee[0])) | ((s >= ss[1]) & (s < ee[1])) |
            ((s >= ss[2]) & (s < ee[2])) | ((s >= ss[3]) & (s < ee[3]));
        tv[i] = cov;
        cv[i] = cov ^ 1;
        // padded_positions[k]: k-th masked position, else sentinel S_LEN.
        // Empty segments have zero width in the cumulative brackets, so the
        // select chain skips them naturally.
        int v;
        if      (s >= total) v = S_LEN;
        else if (s >= c3)    v = L3 + (s - c3);
        else if (s >= c2)    v = L2 + (s - c2);
        else if (s >= c1)    v = L1 + (s - c1);
        else                 v = L0 + s;
        pv[i] = v;
    }

    reinterpret_cast<int4*>(ctx + p0)[0] = make_int4(cv[0], cv[1], cv[2], cv[3]);
    reinterpret_cast<int4*>(ctx + p0)[1] = make_int4(cv[4], cv[5], cv[6], cv[7]);
    reinterpret_cast<int4*>(tgt + p0)[0] = make_int4(tv[0], tv[1], tv[2], tv[3]);
    reinterpret_cast<int4*>(tgt + p0)[1] = make_int4(tv[4], tv[5], tv[6], tv[7]);
    reinterpret_cast<int4*>(pad + p0)[0] = make_int4(pv[0], pv[1], pv[2], pv[3]);
    reinterpret_cast<int4*>(pad + p0)[1] = make_int4(pv[4], pv[5], pv[6], pv[7]);
}

extern "C" void kernel_launch(void* const* d_in, const int* in_sizes, int n_in,
                              void* d_out, int out_size, void* d_ws, size_t ws_size,
                              hipStream_t stream)
{
    const float* scales_u = (const float*)d_in[0];
    const float* starts_u = (const float*)d_in[1];
    // d_in[2]/d_in[3] are batch_size=256 / seq_len=131072 scalars (fixed).
    const int batch = 256;
    dim3 grid(S_LEN / (TPB * ITEMS), batch);   // (64, 256)
    span_mask_kernel<<<grid, dim3(TPB), 0, stream>>>(
        scales_u, starts_u, (int*)d_out, batch);
}